// Round 8
// baseline (218.754 us; speedup 1.0000x reference)
//
#include <hip/hip_runtime.h>
#include <hip/hip_fp16.h>
#include <cstdint>
#include <cmath>

#define QP    127.0f
#define MINR  1e-6f

// Problem dims: B*N = 8192 tokens, D = 1024, H = 4096
#define MTOK 8192
#define DDIM 1024
#define HDIM 4096

typedef __attribute__((ext_vector_type(4))) int int32x4;
typedef __attribute__((ext_vector_type(8))) short short8;

__device__ __forceinline__ void gload16(const void* g, void* l) {
    __builtin_amdgcn_global_load_lds(
        (const __attribute__((address_space(1))) void*)g,
        (__attribute__((address_space(3))) void*)l, 16, 0, 0);
}

__global__ void zero_scales_kernel(float* g) {
    if (threadIdx.x < 4) g[threadIdx.x] = 0.0f;
}

// ---- fused 3-tensor absmax: block-range partition, atomicMax per tensor ----
__device__ __forceinline__ float wave_block_max(float m) {
    #pragma unroll
    for (int off = 32; off; off >>= 1) m = fmaxf(m, __shfl_down(m, off));
    __shared__ float sm[4];
    int lane = threadIdx.x & 63, w = threadIdx.x >> 6;
    if (lane == 0) sm[w] = m;
    __syncthreads();
    float bm = 0.0f;
    if (threadIdx.x == 0) bm = fmaxf(fmaxf(sm[0], sm[1]), fmaxf(sm[2], sm[3]));
    return bm;
}

__device__ __forceinline__ void absmax_range(const float4* in4, int n4, int bid, int nb,
                                             float* gout) {
    int tid = bid * blockDim.x + threadIdx.x;
    int stride = nb * blockDim.x;
    float m = 0.0f;
    for (int i = tid; i < n4; i += stride) {
        float4 v = in4[i];
        m = fmaxf(m, fmaxf(fmaxf(fabsf(v.x), fabsf(v.y)), fmaxf(fabsf(v.z), fabsf(v.w))));
    }
    float bm = wave_block_max(m);
    if (threadIdx.x == 0) atomicMax((int*)gout, __float_as_int(bm));
}

// blocks [0,1024) -> x, [1024,1536) -> w1, [1536,2048) -> w2
__global__ void absmax3_kernel(const float* __restrict__ x, const float* __restrict__ w1,
                               const float* __restrict__ w2, float* __restrict__ gmax) {
    int b = blockIdx.x;
    if (b < 1024)      absmax_range((const float4*)x,  MTOK * DDIM / 4, b,        1024, gmax + 0);
    else if (b < 1536) absmax_range((const float4*)w1, HDIM * DDIM / 4, b - 1024,  512, gmax + 1);
    else               absmax_range((const float4*)w2, DDIM * HDIM / 4, b - 1536,  512, gmax + 3);
}

__device__ __forceinline__ void quant_range(const float4* in4, int* out4, int n4,
                                            int bid, int nb, const float* gm) {
    const float s = fmaxf(*gm, MINR) / QP;
    int tid = bid * blockDim.x + threadIdx.x;
    int stride = nb * blockDim.x;
    for (int i = tid; i < n4; i += stride) {
        float4 v = in4[i];
        int q0 = ((int)rintf(v.x / s)) & 255;
        int q1 = ((int)rintf(v.y / s)) & 255;
        int q2 = ((int)rintf(v.z / s)) & 255;
        int q3 = ((int)rintf(v.w / s)) & 255;
        out4[i] = q0 | (q1 << 8) | (q2 << 16) | (q3 << 24);
    }
}

// blocks [0,2048) -> x, [2048,3072) -> w1, [3072,4096) -> w2
__global__ void quant3_kernel(const float* __restrict__ x, const float* __restrict__ w1,
                              const float* __restrict__ w2, int8_t* __restrict__ xq,
                              int8_t* __restrict__ w1q, int8_t* __restrict__ w2q,
                              const float* __restrict__ gmax) {
    int b = blockIdx.x;
    if (b < 2048)      quant_range((const float4*)x,  (int*)xq,  MTOK * DDIM / 4, b,        2048, gmax + 0);
    else if (b < 3072) quant_range((const float4*)w1, (int*)w1q, HDIM * DDIM / 4, b - 2048, 1024, gmax + 1);
    else               quant_range((const float4*)w2, (int*)w2q, DDIM * HDIM / 4, b - 3072, 1024, gmax + 3);
}

// quantize h (fp16) -> int8.  8 halves per thread-iter (16B loads, 8B stores).
__global__ void quant_h_kernel(const __half* __restrict__ h, int8_t* __restrict__ hq,
                               const float* __restrict__ gm) {
    const float s = fmaxf(*gm, MINR) / QP;
    const short8* in8 = (const short8*)h;
    int2* out8 = (int2*)hq;
    const int n8 = MTOK * HDIM / 8;
    int tid = blockIdx.x * blockDim.x + threadIdx.x;
    int stride = gridDim.x * blockDim.x;
    for (int i = tid; i < n8; i += stride) {
        short8 v = in8[i];
        int q[8];
        #pragma unroll
        for (int j = 0; j < 8; ++j) {
            __half_raw r; r.x = (unsigned short)v[j];
            float f = __half2float(__half(r));
            q[j] = ((int)rintf(f / s)) & 255;
        }
        int2 o;
        o.x = q[0] | (q[1] << 8) | (q[2] << 16) | (q[3] << 24);
        o.y = q[4] | (q[5] << 8) | (q[6] << 16) | (q[7] << 24);
        out8[i] = o;
    }
}

// ---------------------------------------------------------------------------
// Round-8: high-intensity tile on the PROVEN 2-barrier loop.
// BM=256 x BN (256 for GEMM1, 128 for GEMM2), 512 threads = 8 waves (2M x 4N),
// per-wave output 128 x BN/4, acc[8][BN/64].  Single-buffered LDS (32+BN/8 KB),
// stage -> __syncthreads -> compute -> __syncthreads, mfma_i32_16x16x64_i8,
// linear-dest global_load_lds + source pre-swizzle + XOR-swizzled ds_read_b128.
// Rationale: measured step cost has a ~1000-cyc size-independent latency tail;
// 256-wide tiles double MFMA-per-staged-byte and cut step-slots per CU
// (GEMM1: 64 -> 16), with 1 block/CU so no in-phase VMEM contention (R4's
// failure).  Natural 2D grid, bc fastest (R1's measured-good L2 pattern).
// ---------------------------------------------------------------------------
template<int KD, int ND, int BN, bool GELU_EPI, typename OUTT>
__global__ __launch_bounds__(512, 2)
void gemm_i8_kernel(const int8_t* __restrict__ A, const int8_t* __restrict__ B,
                    const float* __restrict__ bias,
                    const float* __restrict__ gmA, const float* __restrict__ gmB,
                    OUTT* __restrict__ out, float* __restrict__ omax) {
    constexpr int BM = 256;
    constexpr int NF = (BN / 4) / 16;      // N fragments per wave: 4 or 2
    __shared__ int8_t lA[BM * 128];        // 32 KB
    __shared__ int8_t lB[BN * 128];        // 32 or 16 KB
    const int t = threadIdx.x;
    const int lane = t & 63;
    const int w = t >> 6;                  // 0..7
    const int wm = (w >> 2) * 128;         // 0 / 128
    const int wn = (w & 3) * (BN / 4);     // N offset per wave
    const int lr = lane & 15;
    const int lg = lane >> 4;
    const int br = blockIdx.y, bc = blockIdx.x;

    const int8_t* Ab = A + (size_t)br * BM * KD;
    const int8_t* Bb = B + (size_t)bc * BN * KD;

    int32x4 acc[8][NF] = {};

    for (int kt = 0; kt < KD / 128; ++kt) {
        // stage A: 2048 x 16B chunks (4/thread); B: BN*8 chunks (BN/64 per thread)
        #pragma unroll
        for (int i = 0; i < 4; ++i) {
            int c = t + i * 512;
            int r = c >> 3;                // 0..255
            int sl = c & 7;
            gload16(Ab + (size_t)r * KD + kt * 128 + ((sl ^ (r & 7)) << 4), &lA[c * 16]);
        }
        #pragma unroll
        for (int i = 0; i < BN / 64; ++i) {
            int c = t + i * 512;
            int r = c >> 3;                // 0..BN-1
            int sl = c & 7;
            gload16(Bb + (size_t)r * KD + kt * 128 + ((sl ^ (r & 7)) << 4), &lB[c * 16]);
        }
        __syncthreads();

        #pragma unroll
        for (int kk = 0; kk < 2; ++kk) {
            int32x4 af[8], bf[NF];
            #pragma unroll
            for (int m = 0; m < 8; ++m) {
                int r = wm + m * 16 + lr;
                int g = kk * 4 + lg;
                af[m] = *(const int32x4*)&lA[r * 128 + ((g ^ (r & 7)) << 4)];
            }
            #pragma unroll
            for (int n = 0; n < NF; ++n) {
                int r = wn + n * 16 + lr;
                int g = kk * 4 + lg;
                bf[n] = *(const int32x4*)&lB[r * 128 + ((g ^ (r & 7)) << 4)];
            }
            #pragma unroll
            for (int m = 0; m < 8; ++m)
                #pragma unroll
                for (int n = 0; n < NF; ++n)
                    acc[m][n] = __builtin_amdgcn_mfma_i32_16x16x64_i8(af[m], bf[n], acc[m][n], 0, 0, 0);
        }
        __syncthreads();
    }

    // epilogue — replicate reference fp32 op order exactly; absmax from the
    // full-precision fp32 value (scale semantics preserved for fp16 h out)
    const float sA = fmaxf(*gmA, MINR) / QP;
    const float sB = fmaxf(*gmB, MINR) / QP;
    const float s = sB * sA;
    float lmax = 0.0f;
    #pragma unroll
    for (int m = 0; m < 8; ++m) {
        #pragma unroll
        for (int n = 0; n < NF; ++n) {
            #pragma unroll
            for (int r = 0; r < 4; ++r) {
                int row = br * BM + wm + m * 16 + lg * 4 + r;
                int col = bc * BN + wn + n * 16 + lr;
                float f = (float)acc[m][n][r] + bias[col];
                f *= s;
                if (GELU_EPI) {
                    float gg = f * (erff(f / 1.41421356237309504880f) + 1.0f) * 0.5f;
                    out[(size_t)row * ND + col] = (OUTT)gg;
                    lmax = fmaxf(lmax, fabsf(gg));
                } else {
                    out[(size_t)row * ND + col] = (OUTT)f;
                }
            }
        }
    }
    if (GELU_EPI) {
        #pragma unroll
        for (int off = 32; off; off >>= 1) lmax = fmaxf(lmax, __shfl_down(lmax, off));
        __shared__ float red[8];
        if (lane == 0) red[w] = lmax;
        __syncthreads();
        if (t == 0) {
            float bm = red[0];
            #pragma unroll
            for (int i = 1; i < 8; ++i) bm = fmaxf(bm, red[i]);
            atomicMax((int*)omax, __float_as_int(bm));
        }
    }
}

extern "C" void kernel_launch(void* const* d_in, const int* in_sizes, int n_in,
                              void* d_out, int out_size, void* d_ws, size_t ws_size,
                              hipStream_t stream) {
    const float* x  = (const float*)d_in[0];   // [8192, 1024]
    const float* w1 = (const float*)d_in[1];   // [4096, 1024]
    const float* b1 = (const float*)d_in[2];   // [4096]
    const float* w2 = (const float*)d_in[3];   // [1024, 4096]
    const float* b2 = (const float*)d_in[4];   // [1024]
    float* out = (float*)d_out;                // [8192, 1024]

    uint8_t* ws = (uint8_t*)d_ws;
    float*  gmax = (float*)ws;                           // [0]=x [1]=w1 [2]=h [3]=w2
    int8_t* xq   = (int8_t*)(ws + 256);                  // 8 MiB
    int8_t* w1q  = xq  + (size_t)MTOK * DDIM;            // 4 MiB
    int8_t* w2q  = w1q + (size_t)HDIM * DDIM;            // 4 MiB
    int8_t* hq   = w2q + (size_t)DDIM * HDIM;            // 32 MiB
    __half* h    = (__half*)(hq + (size_t)MTOK * HDIM);  // 64 MiB fp16

    zero_scales_kernel<<<1, 64, 0, stream>>>(gmax);

    absmax3_kernel<<<2048, 256, 0, stream>>>(x, w1, w2, gmax);
    quant3_kernel<<<4096, 256, 0, stream>>>(x, w1, w2, xq, w1q, w2q, gmax);

    // h(fp16) = gelu((xq @ w1q^T + b1) * s1), fused fp32 absmax(h) -> gmax[2]
    // grid = (4096/256, 8192/256) = (16, 32) = 512 blocks, 2 passes/CU
    gemm_i8_kernel<DDIM, HDIM, 256, true, __half>
        <<<dim3(16, 32), 512, 0, stream>>>(xq, w1q, b1, gmax + 0, gmax + 1, h, gmax + 2);

    quant_h_kernel<<<2048, 256, 0, stream>>>(h, hq, gmax + 2);

    // out = (hq @ w2q^T + b2) * s2
    // grid = (1024/128, 8192/256) = (8, 32) = 256 blocks, exactly 1/CU
    gemm_i8_kernel<HDIM, DDIM, 128, false, float>
        <<<dim3(8, 32), 512, 0, stream>>>(hq, w2q, b2, gmax + 2, gmax + 3, out, nullptr);
}

// Round 9
// 213.217 us; speedup vs baseline: 1.0260x; 1.0260x over previous
//
#include <hip/hip_runtime.h>
#include <hip/hip_fp16.h>
#include <cstdint>
#include <cmath>

#define QP    127.0f
#define MINR  1e-6f

// Problem dims: B*N = 8192 tokens, D = 1024, H = 4096
#define MTOK 8192
#define DDIM 1024
#define HDIM 4096

typedef __attribute__((ext_vector_type(4))) int int32x4;
typedef __attribute__((ext_vector_type(8))) short short8;

__device__ __forceinline__ void gload16(const void* g, void* l) {
    __builtin_amdgcn_global_load_lds(
        (const __attribute__((address_space(1))) void*)g,
        (__attribute__((address_space(3))) void*)l, 16, 0, 0);
}

__global__ void zero_scales_kernel(float* g) {
    if (threadIdx.x < 4) g[threadIdx.x] = 0.0f;
}

// ---- fused 3-tensor absmax: block-range partition, atomicMax per tensor ----
__device__ __forceinline__ float wave_block_max(float m) {
    #pragma unroll
    for (int off = 32; off; off >>= 1) m = fmaxf(m, __shfl_down(m, off));
    __shared__ float sm[4];
    int lane = threadIdx.x & 63, w = threadIdx.x >> 6;
    if (lane == 0) sm[w] = m;
    __syncthreads();
    float bm = 0.0f;
    if (threadIdx.x == 0) bm = fmaxf(fmaxf(sm[0], sm[1]), fmaxf(sm[2], sm[3]));
    return bm;
}

__device__ __forceinline__ void absmax_range(const float4* in4, int n4, int bid, int nb,
                                             float* gout) {
    int tid = bid * blockDim.x + threadIdx.x;
    int stride = nb * blockDim.x;
    float m = 0.0f;
    for (int i = tid; i < n4; i += stride) {
        float4 v = in4[i];
        m = fmaxf(m, fmaxf(fmaxf(fabsf(v.x), fabsf(v.y)), fmaxf(fabsf(v.z), fabsf(v.w))));
    }
    float bm = wave_block_max(m);
    if (threadIdx.x == 0) atomicMax((int*)gout, __float_as_int(bm));
}

// blocks [0,1024) -> x, [1024,1536) -> w1, [1536,2048) -> w2
__global__ void absmax3_kernel(const float* __restrict__ x, const float* __restrict__ w1,
                               const float* __restrict__ w2, float* __restrict__ gmax) {
    int b = blockIdx.x;
    if (b < 1024)      absmax_range((const float4*)x,  MTOK * DDIM / 4, b,        1024, gmax + 0);
    else if (b < 1536) absmax_range((const float4*)w1, HDIM * DDIM / 4, b - 1024,  512, gmax + 1);
    else               absmax_range((const float4*)w2, DDIM * HDIM / 4, b - 1536,  512, gmax + 3);
}

__device__ __forceinline__ void quant_range(const float4* in4, int* out4, int n4,
                                            int bid, int nb, const float* gm) {
    const float s = fmaxf(*gm, MINR) / QP;
    int tid = bid * blockDim.x + threadIdx.x;
    int stride = nb * blockDim.x;
    for (int i = tid; i < n4; i += stride) {
        float4 v = in4[i];
        int q0 = ((int)rintf(v.x / s)) & 255;
        int q1 = ((int)rintf(v.y / s)) & 255;
        int q2 = ((int)rintf(v.z / s)) & 255;
        int q3 = ((int)rintf(v.w / s)) & 255;
        out4[i] = q0 | (q1 << 8) | (q2 << 16) | (q3 << 24);
    }
}

// blocks [0,2048) -> x, [2048,3072) -> w1, [3072,4096) -> w2
__global__ void quant3_kernel(const float* __restrict__ x, const float* __restrict__ w1,
                              const float* __restrict__ w2, int8_t* __restrict__ xq,
                              int8_t* __restrict__ w1q, int8_t* __restrict__ w2q,
                              const float* __restrict__ gmax) {
    int b = blockIdx.x;
    if (b < 2048)      quant_range((const float4*)x,  (int*)xq,  MTOK * DDIM / 4, b,        2048, gmax + 0);
    else if (b < 3072) quant_range((const float4*)w1, (int*)w1q, HDIM * DDIM / 4, b - 2048, 1024, gmax + 1);
    else               quant_range((const float4*)w2, (int*)w2q, DDIM * HDIM / 4, b - 3072, 1024, gmax + 3);
}

// quantize h (fp16) -> int8.  8 halves per thread-iter (16B loads, 8B stores).
__global__ void quant_h_kernel(const __half* __restrict__ h, int8_t* __restrict__ hq,
                               const float* __restrict__ gm) {
    const float s = fmaxf(*gm, MINR) / QP;
    const short8* in8 = (const short8*)h;
    int2* out8 = (int2*)hq;
    const int n8 = MTOK * HDIM / 8;
    int tid = blockIdx.x * blockDim.x + threadIdx.x;
    int stride = gridDim.x * blockDim.x;
    for (int i = tid; i < n8; i += stride) {
        short8 v = in8[i];
        int q[8];
        #pragma unroll
        for (int j = 0; j < 8; ++j) {
            __half_raw r; r.x = (unsigned short)v[j];
            float f = __half2float(__half(r));
            q[j] = ((int)rintf(f / s)) & 255;
        }
        int2 o;
        o.x = q[0] | (q[1] << 8) | (q[2] << 16) | (q[3] << 24);
        o.y = q[4] | (q[5] << 8) | (q[6] << 16) | (q[7] << 24);
        out8[i] = o;
    }
}

// ---------------------------------------------------------------------------
// Round-9 GEMM: R1's exact budget (per GEMM1 block: 64 gloads, 128 ds_reads,
// 256 MFMA, 16 barriers) reshaped as a BK=64 double-buffer:
//   - LDS halves to 32 KB (2 buf x [128 rows x 64 B] x {A,B}) -> LDS allows
//     4 blocks/CU (regs ~3): keeps the cross-block drain-hiding R1 relied on;
//   - step = { stage(next buf) ; compute(cur buf) ; vmcnt(0)+barrier }: the
//     drain now sits AFTER ~640 cyc of MFMA/ds_read instead of right after
//     issue (in-block prefetch at zero LDS/reg cost);
//   - buffer indices are macro-constant so alias analysis can prove the
//     staged buffer != computed buffer (no conservative vmcnt before ds_read).
// Bank math (64-B rows): read slot = lg ^ (lr&3) ^ ((lr>>2)&3) is lane-
// constant; distinct (row parity, slot) pairs give exactly 2-way aliasing =
// free (m136).  Staging source pre-swizzled with the same involution, LDS
// dest linear (G21).  mfma_i32_16x16x64_i8, natural 2D grid (bc fastest).
// ---------------------------------------------------------------------------
template<int KD, int ND, bool GELU_EPI, typename OUTT>
__global__ __launch_bounds__(256, 2)
void gemm_i8_kernel(const int8_t* __restrict__ A, const int8_t* __restrict__ B,
                    const float* __restrict__ bias,
                    const float* __restrict__ gmA, const float* __restrict__ gmB,
                    OUTT* __restrict__ out, float* __restrict__ omax) {
    constexpr int KT = KD / 64;            // 16 (GEMM1) / 64 (GEMM2), even
    __shared__ int8_t lA[2 * 128 * 64];    // 16 KB
    __shared__ int8_t lB[2 * 128 * 64];    // 16 KB
    const int t = threadIdx.x;
    const int lane = t & 63;
    const int w = t >> 6;
    const int wm = (w >> 1) * 64;
    const int wn = (w & 1) * 64;
    const int lr = lane & 15;
    const int lg = lane >> 4;
    const int br = blockIdx.y, bc = blockIdx.x;

    const int8_t* Ab = A + (size_t)br * 128 * KD;
    const int8_t* Bb = B + (size_t)bc * 128 * KD;

    // lane-constant read slot within a 64-B row (2-way bank aliasing = free)
    const int swz = ((lg ^ (lr & 3) ^ ((lr >> 2) & 3)) << 4);

    int32x4 acc[4][4] = {};

// stage K-tile kt_ into buffer S (S is a literal): 512 chunks x 16 B per
// matrix, 2/thread; linear LDS dest, source slot pre-swizzled (involution)
#define STAGE(S, kt_) do {                                                        \
        _Pragma("unroll") for (int i_ = 0; i_ < 2; ++i_) {                        \
            int c_ = t + i_ * 256;          /* 0..511 */                          \
            int r_ = c_ >> 2;               /* row 0..127 */                      \
            int sl_ = c_ & 3;               /* 16B slot 0..3 */                   \
            int sc_ = ((sl_ ^ (r_ & 3) ^ ((r_ >> 2) & 3)) << 4);                  \
            gload16(Ab + (size_t)r_ * KD + (kt_) * 64 + sc_, &lA[(S) * 8192 + c_ * 16]); \
            gload16(Bb + (size_t)r_ * KD + (kt_) * 64 + sc_, &lB[(S) * 8192 + c_ * 16]); \
        } } while (0)

#define COMPUTE(S) do {                                                           \
        int32x4 af[4], bf[4];                                                     \
        _Pragma("unroll") for (int m = 0; m < 4; ++m)                             \
            af[m] = *(const int32x4*)&lA[(S) * 8192 + (wm + m * 16 + lr) * 64 + swz]; \
        _Pragma("unroll") for (int n = 0; n < 4; ++n)                             \
            bf[n] = *(const int32x4*)&lB[(S) * 8192 + (wn + n * 16 + lr) * 64 + swz]; \
        _Pragma("unroll") for (int m = 0; m < 4; ++m)                             \
            _Pragma("unroll") for (int n = 0; n < 4; ++n)                         \
                acc[m][n] = __builtin_amdgcn_mfma_i32_16x16x64_i8(af[m], bf[n], acc[m][n], 0, 0, 0); \
        } while (0)

#define SYNC() do {                                                               \
        asm volatile("s_waitcnt vmcnt(0) lgkmcnt(0)" ::: "memory");               \
        __builtin_amdgcn_s_barrier();                                             \
        asm volatile("" ::: "memory");                                            \
        } while (0)

    STAGE(0, 0);
    SYNC();

    for (int kt = 0; kt < KT; kt += 2) {
        if (kt + 1 < KT) STAGE(1, kt + 1);   // prefetch in flight...
        COMPUTE(0);                           // ...under this buffer's MFMA
        SYNC();
        if (kt + 2 < KT) STAGE(0, kt + 2);
        COMPUTE(1);
        SYNC();
    }
#undef STAGE
#undef COMPUTE
#undef SYNC

    // epilogue — replicate reference fp32 op order exactly; absmax from the
    // full-precision fp32 value (scale semantics preserved for fp16 h out)
    const float sA = fmaxf(*gmA, MINR) / QP;
    const float sB = fmaxf(*gmB, MINR) / QP;
    const float s = sB * sA;
    float lmax = 0.0f;
    #pragma unroll
    for (int m = 0; m < 4; ++m) {
        #pragma unroll
        for (int n = 0; n < 4; ++n) {
            #pragma unroll
            for (int r = 0; r < 4; ++r) {
                int row = br * 128 + wm + m * 16 + lg * 4 + r;
                int col = bc * 128 + wn + n * 16 + lr;
                float f = (float)acc[m][n][r] + bias[col];
                f *= s;
                if (GELU_EPI) {
                    float gg = f * (erff(f / 1.41421356237309504880f) + 1.0f) * 0.5f;
                    out[(size_t)row * ND + col] = (OUTT)gg;
                    lmax = fmaxf(lmax, fabsf(gg));
                } else {
                    out[(size_t)row * ND + col] = (OUTT)f;
                }
            }
        }
    }
    if (GELU_EPI) {
        #pragma unroll
        for (int off = 32; off; off >>= 1) lmax = fmaxf(lmax, __shfl_down(lmax, off));
        __shared__ float red[4];
        if (lane == 0) red[w] = lmax;
        __syncthreads();
        if (t == 0) {
            float bm = fmaxf(fmaxf(red[0], red[1]), fmaxf(red[2], red[3]));
            atomicMax((int*)omax, __float_as_int(bm));
        }
    }
}

extern "C" void kernel_launch(void* const* d_in, const int* in_sizes, int n_in,
                              void* d_out, int out_size, void* d_ws, size_t ws_size,
                              hipStream_t stream) {
    const float* x  = (const float*)d_in[0];   // [8192, 1024]
    const float* w1 = (const float*)d_in[1];   // [4096, 1024]
    const float* b1 = (const float*)d_in[2];   // [4096]
    const float* w2 = (const float*)d_in[3];   // [1024, 4096]
    const float* b2 = (const float*)d_in[4];   // [1024]
    float* out = (float*)d_out;                // [8192, 1024]

    uint8_t* ws = (uint8_t*)d_ws;
    float*  gmax = (float*)ws;                           // [0]=x [1]=w1 [2]=h [3]=w2
    int8_t* xq   = (int8_t*)(ws + 256);                  // 8 MiB
    int8_t* w1q  = xq  + (size_t)MTOK * DDIM;            // 4 MiB
    int8_t* w2q  = w1q + (size_t)HDIM * DDIM;            // 4 MiB
    int8_t* hq   = w2q + (size_t)DDIM * HDIM;            // 32 MiB
    __half* h    = (__half*)(hq + (size_t)MTOK * HDIM);  // 64 MiB fp16

    zero_scales_kernel<<<1, 64, 0, stream>>>(gmax);

    absmax3_kernel<<<2048, 256, 0, stream>>>(x, w1, w2, gmax);
    quant3_kernel<<<4096, 256, 0, stream>>>(x, w1, w2, xq, w1q, w2q, gmax);

    // h(fp16) = gelu((xq @ w1q^T + b1) * s1), fused fp32 absmax(h) -> gmax[2]
    // grid = (4096/128, 8192/128) = (32, 64), bc fastest (R1's L2 pattern)
    gemm_i8_kernel<DDIM, HDIM, true, __half>
        <<<dim3(32, 64), 256, 0, stream>>>(xq, w1q, b1, gmax + 0, gmax + 1, h, gmax + 2);

    quant_h_kernel<<<2048, 256, 0, stream>>>(h, hq, gmax + 2);

    // out = (hq @ w2q^T + b2) * s2 ; grid = (1024/128, 8192/128) = (8, 64)
    gemm_i8_kernel<HDIM, DDIM, false, float>
        <<<dim3(8, 64), 256, 0, stream>>>(hq, w2q, b2, gmax + 2, gmax + 3, out, nullptr);
}

// Round 11
// 202.859 us; speedup vs baseline: 1.0784x; 1.0511x over previous
//
#include <hip/hip_runtime.h>
#include <hip/hip_fp16.h>
#include <cstdint>
#include <cmath>

#define QP    127.0f
#define MINR  1e-6f

// Problem dims: B*N = 8192 tokens, D = 1024, H = 4096
#define MTOK 8192
#define DDIM 1024
#define HDIM 4096

typedef __attribute__((ext_vector_type(4))) int int32x4;
typedef __attribute__((ext_vector_type(8))) short short8;

__device__ __forceinline__ void gload16(const void* g, void* l) {
    __builtin_amdgcn_global_load_lds(
        (const __attribute__((address_space(1))) void*)g,
        (__attribute__((address_space(3))) void*)l, 16, 0, 0);
}

template<int N> __device__ __forceinline__ void wait_vmcnt() {
    if constexpr (N == 0) asm volatile("s_waitcnt vmcnt(0)" ::: "memory");
    else if constexpr (N == 2) asm volatile("s_waitcnt vmcnt(2)" ::: "memory");
    else if constexpr (N == 3) asm volatile("s_waitcnt vmcnt(3)" ::: "memory");
    else if constexpr (N == 4) asm volatile("s_waitcnt vmcnt(4)" ::: "memory");
}

__device__ __forceinline__ void barf() {
    __builtin_amdgcn_s_barrier();
    asm volatile("" ::: "memory");
}

__global__ void zero_scales_kernel(float* g) {
    if (threadIdx.x < 4) g[threadIdx.x] = 0.0f;
}

// ---- fused 3-tensor absmax ----
__device__ __forceinline__ float wave_block_max(float m) {
    #pragma unroll
    for (int off = 32; off; off >>= 1) m = fmaxf(m, __shfl_down(m, off));
    __shared__ float sm[4];
    int lane = threadIdx.x & 63, w = threadIdx.x >> 6;
    if (lane == 0) sm[w] = m;
    __syncthreads();
    float bm = 0.0f;
    if (threadIdx.x == 0) bm = fmaxf(fmaxf(sm[0], sm[1]), fmaxf(sm[2], sm[3]));
    return bm;
}

__device__ __forceinline__ void absmax_range(const float4* in4, int n4, int bid, int nb,
                                             float* gout) {
    int tid = bid * blockDim.x + threadIdx.x;
    int stride = nb * blockDim.x;
    float m = 0.0f;
    for (int i = tid; i < n4; i += stride) {
        float4 v = in4[i];
        m = fmaxf(m, fmaxf(fmaxf(fabsf(v.x), fabsf(v.y)), fmaxf(fabsf(v.z), fabsf(v.w))));
    }
    float bm = wave_block_max(m);
    if (threadIdx.x == 0) atomicMax((int*)gout, __float_as_int(bm));
}

__global__ void absmax3_kernel(const float* __restrict__ x, const float* __restrict__ w1,
                               const float* __restrict__ w2, float* __restrict__ gmax) {
    int b = blockIdx.x;
    if (b < 1024)      absmax_range((const float4*)x,  MTOK * DDIM / 4, b,        1024, gmax + 0);
    else if (b < 1536) absmax_range((const float4*)w1, HDIM * DDIM / 4, b - 1024,  512, gmax + 1);
    else               absmax_range((const float4*)w2, DDIM * HDIM / 4, b - 1536,  512, gmax + 3);
}

__device__ __forceinline__ void quant_range(const float4* in4, int* out4, int n4,
                                            int bid, int nb, const float* gm) {
    const float s = fmaxf(*gm, MINR) / QP;
    int tid = bid * blockDim.x + threadIdx.x;
    int stride = nb * blockDim.x;
    for (int i = tid; i < n4; i += stride) {
        float4 v = in4[i];
        int q0 = ((int)rintf(v.x / s)) & 255;
        int q1 = ((int)rintf(v.y / s)) & 255;
        int q2 = ((int)rintf(v.z / s)) & 255;
        int q3 = ((int)rintf(v.w / s)) & 255;
        out4[i] = q0 | (q1 << 8) | (q2 << 16) | (q3 << 24);
    }
}

__global__ void quant3_kernel(const float* __restrict__ x, const float* __restrict__ w1,
                              const float* __restrict__ w2, int8_t* __restrict__ xq,
                              int8_t* __restrict__ w1q, int8_t* __restrict__ w2q,
                              const float* __restrict__ gmax) {
    int b = blockIdx.x;
    if (b < 2048)      quant_range((const float4*)x,  (int*)xq,  MTOK * DDIM / 4, b,        2048, gmax + 0);
    else if (b < 3072) quant_range((const float4*)w1, (int*)w1q, HDIM * DDIM / 4, b - 2048, 1024, gmax + 1);
    else               quant_range((const float4*)w2, (int*)w2q, DDIM * HDIM / 4, b - 3072, 1024, gmax + 3);
}

__global__ void quant_h_kernel(const __half* __restrict__ h, int8_t* __restrict__ hq,
                               const float* __restrict__ gm) {
    const float s = fmaxf(*gm, MINR) / QP;
    const short8* in8 = (const short8*)h;
    int2* out8 = (int2*)hq;
    const int n8 = MTOK * HDIM / 8;
    int tid = blockIdx.x * blockDim.x + threadIdx.x;
    int stride = gridDim.x * blockDim.x;
    for (int i = tid; i < n8; i += stride) {
        short8 v = in8[i];
        int q[8];
        #pragma unroll
        for (int j = 0; j < 8; ++j) {
            __half_raw r; r.x = (unsigned short)v[j];
            float f = __half2float(__half(r));
            q[j] = ((int)rintf(f / s)) & 255;
        }
        int2 o;
        o.x = q[0] | (q[1] << 8) | (q[2] << 16) | (q[3] << 24);
        o.y = q[4] | (q[5] << 8) | (q[6] << 16) | (q[7] << 24);
        out8[i] = o;
    }
}

// ---------------------------------------------------------------------------
// GEMM1: 256x256 8-phase i8 kernel (R10 fixed).  The R10 correctness bug was
// contiguous stage-halves vs interleaved phase-reads; now stage-half h covers
// A rows {(r/64)%2==h} and B rows {(r/32)%2==h}, so phase (mh,nh) reads
// EXACTLY halves (mh,nh) and the counted-vmcnt ledger guarantees hold:
//   prologue wait<2>; steady waits <3>@p0, <4>@p3, <3>@p4, <4>@p7 (closed at
//   4 outstanding); last-iter drains <2>@p3, <0>@p4.  Every stage overwrites
//   a region one phase after its last reader (behind a barrier).
// LDS: 2 slots x (A 16KB + B 16KB) = 64 KB.  K-tiles = 64 B stored as 128-B
// lines (2 rows/line, slot = ((parity<<2)|chunk) ^ (line&7)) -> R1's proven
// conflict-free 8-slot class.  8 waves (2M x 4N), 2 barriers/phase,
// 6 ds_read_b128 + <=1 gload_lds per phase, setprio around the MFMA cluster.
// ---------------------------------------------------------------------------
__global__ __launch_bounds__(512, 2)
void gemm8_i8_g1(const int8_t* __restrict__ A, const int8_t* __restrict__ B,
                 const float* __restrict__ bias,
                 const float* __restrict__ gmA, const float* __restrict__ gmB,
                 __half* __restrict__ out, float* __restrict__ omax) {
    constexpr int KD = DDIM;               // 1024
    constexpr int ND = HDIM;               // 4096
    constexpr int ITER = (KD / 64) / 2;    // 8

    __shared__ int8_t lA[2 * 16384];
    __shared__ int8_t lB[2 * 16384];

    const int t = threadIdx.x;
    const int lane = t & 63;
    const int w = t >> 6;
    const int wr = w >> 2;                 // 0..1
    const int wc = w & 3;                  // 0..3
    const int lr = lane & 15;
    const int lg = lane >> 4;
    const int br = blockIdx.y, bc = blockIdx.x;

    const int8_t* Ab = A + (size_t)br * 256 * KD;
    const int8_t* Bb = B + (size_t)bc * 256 * KD;

    // staging: thread t fills LDS bytes [t*16, t*16+16) of an 8 KB half-slab.
    // line lam holds rows 2*lam, 2*lam+1; slot = ((parity<<2)|chunk)^(lam&7).
    const int lam  = t >> 3;                       // line in half, 0..63
    const int s8p  = (t & 7) ^ (lam & 7);
    const int arow = (lam << 1) + (s8p >> 2);      // stage-local row 0..127
    const int scol = (s8p & 3) << 4;               // source 16-B chunk
    const int ldst = t * 16;
    // interleaved half mapping: A half h = rows {(r/64)%2==h}; B: {(r/32)%2==h}
    const int grA = (arow & 63) + ((arow >> 6) << 7);   // + MH*64 at use
    const int grB = (arow & 31) + ((arow >> 5) << 6);   // + NH*32 at use

    // reads: lane-constant slot, line&7 == lr>>1 for all fragments
    const int s8  = (((((lr & 1) << 2) | lg) ^ (lr >> 1)) << 4);
    const int rbA = (wr * 32 + (lr >> 1)) * 128 + s8;
    const int rbB = (wc * 16 + (lr >> 1)) * 128 + s8;

    int32x4 acc[8][4] = {};

#define STA(S, MH, kt_) gload16(Ab + (size_t)(grA + (MH) * 64) * KD + (kt_) * 64 + scol, \
                                &lA[(S) * 16384 + (MH) * 8192 + ldst])
#define STB(S, NH, kt_) gload16(Bb + (size_t)(grB + (NH) * 32) * KD + (kt_) * 64 + scol, \
                                &lB[(S) * 16384 + (NH) * 8192 + ldst])

#define PHASE(P, ...) do {                                                            \
        constexpr int s_ = (P) >> 2, mh_ = ((P) >> 1) & 1, nh_ = (P) & 1;             \
        int32x4 af[4], bf[2];                                                         \
        _Pragma("unroll") for (int m = 0; m < 4; ++m)                                 \
            af[m] = *(const int32x4*)&lA[s_ * 16384 + mh_ * 8192 + rbA + m * 1024];   \
        _Pragma("unroll") for (int n = 0; n < 2; ++n)                                 \
            bf[n] = *(const int32x4*)&lB[s_ * 16384 + nh_ * 8192 + rbB + n * 1024];   \
        __VA_ARGS__;                                                                  \
        barf();                                                                       \
        __builtin_amdgcn_s_setprio(1);                                                \
        _Pragma("unroll") for (int m = 0; m < 4; ++m)                                 \
            _Pragma("unroll") for (int n = 0; n < 2; ++n)                             \
                acc[mh_ * 4 + m][nh_ * 2 + n] = __builtin_amdgcn_mfma_i32_16x16x64_i8(\
                    af[m], bf[n], acc[mh_ * 4 + m][nh_ * 2 + n], 0, 0, 0);            \
        __builtin_amdgcn_s_setprio(0);                                                \
    } while (0)

    // prologue: tile0 all 4 halves -> slot0; tile1 (A h0, B h0) -> slot1
    STA(0, 0, 0); STB(0, 0, 0); STA(0, 1, 0); STB(0, 1, 0);
    STA(1, 0, 1); STB(1, 0, 1);
    wait_vmcnt<2>(); barf();

    for (int it = 0; it < ITER; ++it) {
        const int k1 = 2 * it + 1, k2 = 2 * it + 2, k3 = 2 * it + 3;
        const bool more = (it + 1 < ITER);
        PHASE(0, STA(1, 1, k1));            wait_vmcnt<3>(); barf();
        PHASE(1, STB(1, 1, k1));            barf();
        PHASE(2, if (more) STA(0, 0, k2));  barf();
        PHASE(3, if (more) STB(0, 0, k2));
            if (more) wait_vmcnt<4>(); else wait_vmcnt<2>();
            barf();
        PHASE(4, if (more) STA(0, 1, k2));
            if (more) wait_vmcnt<3>(); else wait_vmcnt<0>();
            barf();
        PHASE(5, if (more) STB(0, 1, k2));  barf();
        PHASE(6, if (more) STA(1, 0, k3));  barf();
        PHASE(7, if (more) STB(1, 0, k3));
            if (more) wait_vmcnt<4>();
            barf();
    }
#undef PHASE
#undef STA
#undef STB

    // epilogue — reference fp32 op order; absmax from full-precision value
    const float sA = fmaxf(*gmA, MINR) / QP;
    const float sB = fmaxf(*gmB, MINR) / QP;
    const float s = sB * sA;
    float lmax = 0.0f;
    const int rowb = br * 256 + wr * 128 + lg * 4;
    const int colb = bc * 256 + wc * 64 + lr;
    #pragma unroll
    for (int m = 0; m < 8; ++m) {      // m*16 == mh*64 + (m&3)*16
        #pragma unroll
        for (int n = 0; n < 4; ++n) {  // n*16 == nh*32 + (n&1)*16
            #pragma unroll
            for (int r = 0; r < 4; ++r) {
                int row = rowb + m * 16 + r;
                int col = colb + n * 16;
                float f = (float)acc[m][n][r] + bias[col];
                f *= s;
                float gg = f * (erff(f / 1.41421356237309504880f) + 1.0f) * 0.5f;
                out[(size_t)row * ND + col] = (__half)gg;
                lmax = fmaxf(lmax, fabsf(gg));
            }
        }
    }
    #pragma unroll
    for (int off = 32; off; off >>= 1) lmax = fmaxf(lmax, __shfl_down(lmax, off));
    __shared__ float red[8];
    if (lane == 0) red[w] = lmax;
    __syncthreads();
    if (t == 0) {
        float bm = red[0];
        #pragma unroll
        for (int i = 1; i < 8; ++i) bm = fmaxf(bm, red[i]);
        atomicMax((int*)omax, __float_as_int(bm));
    }
}

// ---------------------------------------------------------------------------
// GEMM2: R7's proven kernel, verbatim (83.6 us measured).
// ---------------------------------------------------------------------------
template<int KD, int ND, bool GELU_EPI, typename OUTT>
__global__ __launch_bounds__(256, 2)
void gemm_i8_kernel(const int8_t* __restrict__ A, const int8_t* __restrict__ B,
                    const float* __restrict__ bias,
                    const float* __restrict__ gmA, const float* __restrict__ gmB,
                    OUTT* __restrict__ out, float* __restrict__ omax) {
    constexpr int NBC = ND / 128;
    __shared__ int8_t lA[128 * 128];
    __shared__ int8_t lB[128 * 128];
    const int t = threadIdx.x;
    const int lane = t & 63;
    const int w = t >> 6;
    const int wm = (w >> 1) * 64;
    const int wn = (w & 1) * 64;
    const int lr = lane & 15;
    const int lg = lane >> 4;

    const int chunk = gridDim.x >> 3;
    const int logical = (blockIdx.x & 7) * chunk + (blockIdx.x >> 3);
    const int bc = logical % NBC;
    const int br = logical / NBC;

    const int8_t* Ab = A + (size_t)br * 128 * KD;
    const int8_t* Bb = B + (size_t)bc * 128 * KD;

    int32x4 acc[4][4] = {};

    for (int kt = 0; kt < KD / 128; ++kt) {
        #pragma unroll
        for (int i = 0; i < 4; ++i) {
            int c = t + i * 256;
            int r = c >> 3;
            int sl = c & 7;
            int sc = ((sl ^ (r & 7)) << 4);
            gload16(Ab + (size_t)r * KD + kt * 128 + sc, &lA[c * 16]);
            gload16(Bb + (size_t)r * KD + kt * 128 + sc, &lB[c * 16]);
        }
        __syncthreads();

        #pragma unroll
        for (int kk = 0; kk < 2; ++kk) {
            int32x4 af[4], bf[4];
            #pragma unroll
            for (int m = 0; m < 4; ++m) {
                int r = wm + m * 16 + lr;
                int g = kk * 4 + lg;
                af[m] = *(const int32x4*)&lA[r * 128 + ((g ^ (r & 7)) << 4)];
            }
            #pragma unroll
            for (int n = 0; n < 4; ++n) {
                int r = wn + n * 16 + lr;
                int g = kk * 4 + lg;
                bf[n] = *(const int32x4*)&lB[r * 128 + ((g ^ (r & 7)) << 4)];
            }
            #pragma unroll
            for (int m = 0; m < 4; ++m)
                #pragma unroll
                for (int n = 0; n < 4; ++n)
                    acc[m][n] = __builtin_amdgcn_mfma_i32_16x16x64_i8(af[m], bf[n], acc[m][n], 0, 0, 0);
        }
        __syncthreads();
    }

    const float sA = fmaxf(*gmA, MINR) / QP;
    const float sB = fmaxf(*gmB, MINR) / QP;
    const float s = sB * sA;
    float lmax = 0.0f;
    #pragma unroll
    for (int m = 0; m < 4; ++m) {
        #pragma unroll
        for (int n = 0; n < 4; ++n) {
            #pragma unroll
            for (int r = 0; r < 4; ++r) {
                int row = br * 128 + wm + m * 16 + lg * 4 + r;
                int col = bc * 128 + wn + n * 16 + lr;
                float f = (float)acc[m][n][r] + bias[col];
                f *= s;
                if (GELU_EPI) {
                    float gg = f * (erff(f / 1.41421356237309504880f) + 1.0f) * 0.5f;
                    out[(size_t)row * ND + col] = (OUTT)gg;
                    lmax = fmaxf(lmax, fabsf(gg));
                } else {
                    out[(size_t)row * ND + col] = (OUTT)f;
                }
            }
        }
    }
    if (GELU_EPI) {
        #pragma unroll
        for (int off = 32; off; off >>= 1) lmax = fmaxf(lmax, __shfl_down(lmax, off));
        __shared__ float red[4];
        if (lane == 0) red[w] = lmax;
        __syncthreads();
        if (t == 0) {
            float bm = fmaxf(fmaxf(red[0], red[1]), fmaxf(red[2], red[3]));
            atomicMax((int*)omax, __float_as_int(bm));
        }
    }
}

extern "C" void kernel_launch(void* const* d_in, const int* in_sizes, int n_in,
                              void* d_out, int out_size, void* d_ws, size_t ws_size,
                              hipStream_t stream) {
    const float* x  = (const float*)d_in[0];   // [8192, 1024]
    const float* w1 = (const float*)d_in[1];   // [4096, 1024]
    const float* b1 = (const float*)d_in[2];   // [4096]
    const float* w2 = (const float*)d_in[3];   // [1024, 4096]
    const float* b2 = (const float*)d_in[4];   // [1024]
    float* out = (float*)d_out;                // [8192, 1024]

    uint8_t* ws = (uint8_t*)d_ws;
    float*  gmax = (float*)ws;                           // [0]=x [1]=w1 [2]=h [3]=w2
    int8_t* xq   = (int8_t*)(ws + 256);                  // 8 MiB
    int8_t* w1q  = xq  + (size_t)MTOK * DDIM;            // 4 MiB
    int8_t* w2q  = w1q + (size_t)HDIM * DDIM;            // 4 MiB
    int8_t* hq   = w2q + (size_t)DDIM * HDIM;            // 32 MiB
    __half* h    = (__half*)(hq + (size_t)MTOK * HDIM);  // 64 MiB fp16

    zero_scales_kernel<<<1, 64, 0, stream>>>(gmax);

    absmax3_kernel<<<2048, 256, 0, stream>>>(x, w1, w2, gmax);
    quant3_kernel<<<4096, 256, 0, stream>>>(x, w1, w2, xq, w1q, w2q, gmax);

    // h(fp16) = gelu((xq @ w1q^T + b1) * s1), fused fp32 absmax(h) -> gmax[2]
    // grid = (4096/256, 8192/256) = (16, 32) = 512 blocks, bc fastest
    gemm8_i8_g1<<<dim3(16, 32), 512, 0, stream>>>(xq, w1q, b1, gmax + 0, gmax + 1, h, gmax + 2);

    quant_h_kernel<<<2048, 256, 0, stream>>>(h, hq, gmax + 2);

    // out = (hq @ w2q^T + b2) * s2 ; grid = 512 (%8==0), R7 proven path
    gemm_i8_kernel<HDIM, DDIM, false, float>
        <<<512, 256, 0, stream>>>(hq, w2q, b2, gmax + 2, gmax + 3, out, nullptr);
}

// Round 12
// 194.186 us; speedup vs baseline: 1.1265x; 1.0447x over previous
//
#include <hip/hip_runtime.h>
#include <hip/hip_fp16.h>
#include <cstdint>
#include <cmath>

#define QP    127.0f
#define MINR  1e-6f

// Problem dims: B*N = 8192 tokens, D = 1024, H = 4096
#define MTOK 8192
#define DDIM 1024
#define HDIM 4096

typedef __attribute__((ext_vector_type(4))) int int32x4;
typedef __attribute__((ext_vector_type(8))) short short8;

__device__ __forceinline__ void gload16(const void* g, void* l) {
    __builtin_amdgcn_global_load_lds(
        (const __attribute__((address_space(1))) void*)g,
        (__attribute__((address_space(3))) void*)l, 16, 0, 0);
}

__global__ void zero_scales_kernel(float* g) {
    if (threadIdx.x < 4) g[threadIdx.x] = 0.0f;
}

// ---- fused 3-tensor absmax: block-range partition, atomicMax per tensor ----
__device__ __forceinline__ float wave_block_max(float m) {
    #pragma unroll
    for (int off = 32; off; off >>= 1) m = fmaxf(m, __shfl_down(m, off));
    __shared__ float sm[4];
    int lane = threadIdx.x & 63, w = threadIdx.x >> 6;
    if (lane == 0) sm[w] = m;
    __syncthreads();
    float bm = 0.0f;
    if (threadIdx.x == 0) bm = fmaxf(fmaxf(sm[0], sm[1]), fmaxf(sm[2], sm[3]));
    return bm;
}

__device__ __forceinline__ void absmax_range(const float4* in4, int n4, int bid, int nb,
                                             float* gout) {
    int tid = bid * blockDim.x + threadIdx.x;
    int stride = nb * blockDim.x;
    float m = 0.0f;
    for (int i = tid; i < n4; i += stride) {
        float4 v = in4[i];
        m = fmaxf(m, fmaxf(fmaxf(fabsf(v.x), fabsf(v.y)), fmaxf(fabsf(v.z), fabsf(v.w))));
    }
    float bm = wave_block_max(m);
    if (threadIdx.x == 0) atomicMax((int*)gout, __float_as_int(bm));
}

// blocks [0,1024) -> x, [1024,1536) -> w1, [1536,2048) -> w2
__global__ void absmax3_kernel(const float* __restrict__ x, const float* __restrict__ w1,
                               const float* __restrict__ w2, float* __restrict__ gmax) {
    int b = blockIdx.x;
    if (b < 1024)      absmax_range((const float4*)x,  MTOK * DDIM / 4, b,        1024, gmax + 0);
    else if (b < 1536) absmax_range((const float4*)w1, HDIM * DDIM / 4, b - 1024,  512, gmax + 1);
    else               absmax_range((const float4*)w2, DDIM * HDIM / 4, b - 1536,  512, gmax + 3);
}

__device__ __forceinline__ void quant_range(const float4* in4, int* out4, int n4,
                                            int bid, int nb, const float* gm) {
    const float s = fmaxf(*gm, MINR) / QP;
    int tid = bid * blockDim.x + threadIdx.x;
    int stride = nb * blockDim.x;
    for (int i = tid; i < n4; i += stride) {
        float4 v = in4[i];
        int q0 = ((int)rintf(v.x / s)) & 255;
        int q1 = ((int)rintf(v.y / s)) & 255;
        int q2 = ((int)rintf(v.z / s)) & 255;
        int q3 = ((int)rintf(v.w / s)) & 255;
        out4[i] = q0 | (q1 << 8) | (q2 << 16) | (q3 << 24);
    }
}

// blocks [0,2048) -> x, [2048,3072) -> w1, [3072,4096) -> w2
__global__ void quant3_kernel(const float* __restrict__ x, const float* __restrict__ w1,
                              const float* __restrict__ w2, int8_t* __restrict__ xq,
                              int8_t* __restrict__ w1q, int8_t* __restrict__ w2q,
                              const float* __restrict__ gmax) {
    int b = blockIdx.x;
    if (b < 2048)      quant_range((const float4*)x,  (int*)xq,  MTOK * DDIM / 4, b,        2048, gmax + 0);
    else if (b < 3072) quant_range((const float4*)w1, (int*)w1q, HDIM * DDIM / 4, b - 2048, 1024, gmax + 1);
    else               quant_range((const float4*)w2, (int*)w2q, DDIM * HDIM / 4, b - 3072, 1024, gmax + 3);
}

// quantize h (fp16) -> int8.  8 halves per thread-iter (16B loads, 8B stores).
__global__ void quant_h_kernel(const __half* __restrict__ h, int8_t* __restrict__ hq,
                               const float* __restrict__ gm) {
    const float s = fmaxf(*gm, MINR) / QP;
    const short8* in8 = (const short8*)h;
    int2* out8 = (int2*)hq;
    const int n8 = MTOK * HDIM / 8;
    int tid = blockIdx.x * blockDim.x + threadIdx.x;
    int stride = gridDim.x * blockDim.x;
    for (int i = tid; i < n8; i += stride) {
        short8 v = in8[i];
        int q[8];
        #pragma unroll
        for (int j = 0; j < 8; ++j) {
            __half_raw r; r.x = (unsigned short)v[j];
            float f = __half2float(__half(r));
            q[j] = ((int)rintf(f / s)) & 255;
        }
        int2 o;
        o.x = q[0] | (q[1] << 8) | (q[2] << 16) | (q[3] << 24);
        o.y = q[4] | (q[5] << 8) | (q[6] << 16) | (q[7] << 24);
        out8[i] = o;
    }
}

// ---------------------------------------------------------------------------
// GEMM1 (residency probe): 128x128 tile, BK=64 bytes stored as 128-B LDS
// lines (R11-verified packing, bank conflicts = 0), SINGLE buffer = 16 KB
// LDS total (1/4 of R7), __launch_bounds__(256,4) -> VGPR cap 128 (measured
// structure needs ~72-85) so ~4-6 blocks/CU can co-reside (vs R7's 2.2).
// Staged bytes identical to R7 (537 MB); only residency / step granularity
// change.  Distinguishes H1 (hard ~6.1 TB/s fill-path ceiling: dur flat)
// from H2 (outstanding-limited: dur drops with more in-flight streams).
// Line layout: line L holds rows 2L,2L+1; 16-B slot s of line L holds
// row-parity p=(s^(L&7))>>2, k-chunk c=(s^(L&7))&3.  Read slot
// (((lr&1)<<2)|lg) ^ (lr>>1) is lane-constant; line&7 == lr>>1 for all
// fragments -> conflict-free class.  Source pre-swizzled, LDS dest linear.
// ---------------------------------------------------------------------------
__global__ __launch_bounds__(256, 4)
void gemm_bk64_g1(const int8_t* __restrict__ A, const int8_t* __restrict__ B,
                  const float* __restrict__ bias,
                  const float* __restrict__ gmA, const float* __restrict__ gmB,
                  __half* __restrict__ out, float* __restrict__ omax) {
    constexpr int KD = DDIM;       // 1024
    constexpr int ND = HDIM;       // 4096
    __shared__ int8_t lA[128 * 64];   // 8 KB (64 lines x 128 B)
    __shared__ int8_t lB[128 * 64];   // 8 KB
    const int t = threadIdx.x;
    const int lane = t & 63;
    const int w = t >> 6;
    const int wm = (w >> 1) * 64;
    const int wn = (w & 1) * 64;
    const int lr = lane & 15;
    const int lg = lane >> 4;

    // R7's XCD transform (measured FETCH-positive): bc fastest in logical order
    const int chunk = gridDim.x >> 3;
    const int logical = (blockIdx.x & 7) * chunk + (blockIdx.x >> 3);
    const int bc = logical & 31;           // 4096/128 = 32 columns
    const int br = logical >> 5;

    const int8_t* Ab = A + (size_t)br * 128 * KD;
    const int8_t* Bb = B + (size_t)bc * 128 * KD;

    // staging precompute: chunk c covers LDS bytes [c*16, c*16+16)
    // lam = c>>3 (line), s8p = (c&7)^(lam&7), row = 2*lam + (s8p>>2),
    // source k-offset = (s8p&3)*16
    // read precompute: lane-constant slot, line&7 == lr>>1
    const int s8 = (((((lr & 1) << 2) | lg) ^ (lr >> 1)) << 4);
    const int rbA = wm * 64 + (lr >> 1) * 128 + s8;
    const int rbB = wn * 64 + (lr >> 1) * 128 + s8;

    int32x4 acc[4][4] = {};

    for (int kt = 0; kt < KD / 64; ++kt) {
        #pragma unroll
        for (int i = 0; i < 2; ++i) {
            int c = t + i * 256;           // 0..511
            int lam = c >> 3;
            int s8p = (c & 7) ^ (lam & 7);
            int row = (lam << 1) + (s8p >> 2);
            int scol = (s8p & 3) << 4;
            gload16(Ab + (size_t)row * KD + kt * 64 + scol, &lA[c * 16]);
            gload16(Bb + (size_t)row * KD + kt * 64 + scol, &lB[c * 16]);
        }
        __syncthreads();

        int32x4 af[4], bf[4];
        #pragma unroll
        for (int m = 0; m < 4; ++m)
            af[m] = *(const int32x4*)&lA[rbA + m * 1024];
        #pragma unroll
        for (int n = 0; n < 4; ++n)
            bf[n] = *(const int32x4*)&lB[rbB + n * 1024];
        #pragma unroll
        for (int m = 0; m < 4; ++m)
            #pragma unroll
            for (int n = 0; n < 4; ++n)
                acc[m][n] = __builtin_amdgcn_mfma_i32_16x16x64_i8(af[m], bf[n], acc[m][n], 0, 0, 0);
        __syncthreads();
    }

    // epilogue — reference fp32 op order; absmax from full-precision value
    const float sA = fmaxf(*gmA, MINR) / QP;
    const float sB = fmaxf(*gmB, MINR) / QP;
    const float s = sB * sA;
    float lmax = 0.0f;
    #pragma unroll
    for (int m = 0; m < 4; ++m) {
        #pragma unroll
        for (int n = 0; n < 4; ++n) {
            #pragma unroll
            for (int r = 0; r < 4; ++r) {
                int row = br * 128 + wm + m * 16 + lg * 4 + r;
                int col = bc * 128 + wn + n * 16 + lr;
                float f = (float)acc[m][n][r] + bias[col];
                f *= s;
                float gg = f * (erff(f / 1.41421356237309504880f) + 1.0f) * 0.5f;
                out[(size_t)row * ND + col] = (__half)gg;
                lmax = fmaxf(lmax, fabsf(gg));
            }
        }
    }
    #pragma unroll
    for (int off = 32; off; off >>= 1) lmax = fmaxf(lmax, __shfl_down(lmax, off));
    __shared__ float red[4];
    if (lane == 0) red[w] = lmax;
    __syncthreads();
    if (t == 0) {
        float bm = fmaxf(fmaxf(red[0], red[1]), fmaxf(red[2], red[3]));
        atomicMax((int*)omax, __float_as_int(bm));
    }
}

// ---------------------------------------------------------------------------
// GEMM2: R7's proven kernel, verbatim (83.6 us measured).
// ---------------------------------------------------------------------------
template<int KD, int ND, bool GELU_EPI, typename OUTT>
__global__ __launch_bounds__(256, 2)
void gemm_i8_kernel(const int8_t* __restrict__ A, const int8_t* __restrict__ B,
                    const float* __restrict__ bias,
                    const float* __restrict__ gmA, const float* __restrict__ gmB,
                    OUTT* __restrict__ out, float* __restrict__ omax) {
    constexpr int NBC = ND / 128;
    __shared__ int8_t lA[128 * 128];
    __shared__ int8_t lB[128 * 128];
    const int t = threadIdx.x;
    const int lane = t & 63;
    const int w = t >> 6;
    const int wm = (w >> 1) * 64;
    const int wn = (w & 1) * 64;
    const int lr = lane & 15;
    const int lg = lane >> 4;

    const int chunk = gridDim.x >> 3;
    const int logical = (blockIdx.x & 7) * chunk + (blockIdx.x >> 3);
    const int bc = logical % NBC;
    const int br = logical / NBC;

    const int8_t* Ab = A + (size_t)br * 128 * KD;
    const int8_t* Bb = B + (size_t)bc * 128 * KD;

    int32x4 acc[4][4] = {};

    for (int kt = 0; kt < KD / 128; ++kt) {
        #pragma unroll
        for (int i = 0; i < 4; ++i) {
            int c = t + i * 256;
            int r = c >> 3;
            int sl = c & 7;
            int sc = ((sl ^ (r & 7)) << 4);
            gload16(Ab + (size_t)r * KD + kt * 128 + sc, &lA[c * 16]);
            gload16(Bb + (size_t)r * KD + kt * 128 + sc, &lB[c * 16]);
        }
        __syncthreads();

        #pragma unroll
        for (int kk = 0; kk < 2; ++kk) {
            int32x4 af[4], bf[4];
            #pragma unroll
            for (int m = 0; m < 4; ++m) {
                int r = wm + m * 16 + lr;
                int g = kk * 4 + lg;
                af[m] = *(const int32x4*)&lA[r * 128 + ((g ^ (r & 7)) << 4)];
            }
            #pragma unroll
            for (int n = 0; n < 4; ++n) {
                int r = wn + n * 16 + lr;
                int g = kk * 4 + lg;
                bf[n] = *(const int32x4*)&lB[r * 128 + ((g ^ (r & 7)) << 4)];
            }
            #pragma unroll
            for (int m = 0; m < 4; ++m)
                #pragma unroll
                for (int n = 0; n < 4; ++n)
                    acc[m][n] = __builtin_amdgcn_mfma_i32_16x16x64_i8(af[m], bf[n], acc[m][n], 0, 0, 0);
        }
        __syncthreads();
    }

    const float sA = fmaxf(*gmA, MINR) / QP;
    const float sB = fmaxf(*gmB, MINR) / QP;
    const float s = sB * sA;
    float lmax = 0.0f;
    #pragma unroll
    for (int m = 0; m < 4; ++m) {
        #pragma unroll
        for (int n = 0; n < 4; ++n) {
            #pragma unroll
            for (int r = 0; r < 4; ++r) {
                int row = br * 128 + wm + m * 16 + lg * 4 + r;
                int col = bc * 128 + wn + n * 16 + lr;
                float f = (float)acc[m][n][r] + bias[col];
                f *= s;
                if (GELU_EPI) {
                    float gg = f * (erff(f / 1.41421356237309504880f) + 1.0f) * 0.5f;
                    out[(size_t)row * ND + col] = (OUTT)gg;
                    lmax = fmaxf(lmax, fabsf(gg));
                } else {
                    out[(size_t)row * ND + col] = (OUTT)f;
                }
            }
        }
    }
    if (GELU_EPI) {
        #pragma unroll
        for (int off = 32; off; off >>= 1) lmax = fmaxf(lmax, __shfl_down(lmax, off));
        __shared__ float red[4];
        if (lane == 0) red[w] = lmax;
        __syncthreads();
        if (t == 0) {
            float bm = fmaxf(fmaxf(red[0], red[1]), fmaxf(red[2], red[3]));
            atomicMax((int*)omax, __float_as_int(bm));
        }
    }
}

extern "C" void kernel_launch(void* const* d_in, const int* in_sizes, int n_in,
                              void* d_out, int out_size, void* d_ws, size_t ws_size,
                              hipStream_t stream) {
    const float* x  = (const float*)d_in[0];   // [8192, 1024]
    const float* w1 = (const float*)d_in[1];   // [4096, 1024]
    const float* b1 = (const float*)d_in[2];   // [4096]
    const float* w2 = (const float*)d_in[3];   // [1024, 4096]
    const float* b2 = (const float*)d_in[4];   // [1024]
    float* out = (float*)d_out;                // [8192, 1024]

    uint8_t* ws = (uint8_t*)d_ws;
    float*  gmax = (float*)ws;                           // [0]=x [1]=w1 [2]=h [3]=w2
    int8_t* xq   = (int8_t*)(ws + 256);                  // 8 MiB
    int8_t* w1q  = xq  + (size_t)MTOK * DDIM;            // 4 MiB
    int8_t* w2q  = w1q + (size_t)HDIM * DDIM;            // 4 MiB
    int8_t* hq   = w2q + (size_t)DDIM * HDIM;            // 32 MiB
    __half* h    = (__half*)(hq + (size_t)MTOK * HDIM);  // 64 MiB fp16

    zero_scales_kernel<<<1, 64, 0, stream>>>(gmax);

    absmax3_kernel<<<2048, 256, 0, stream>>>(x, w1, w2, gmax);
    quant3_kernel<<<4096, 256, 0, stream>>>(x, w1, w2, xq, w1q, w2q, gmax);

    // h(fp16) = gelu((xq @ w1q^T + b1) * s1), fused fp32 absmax(h) -> gmax[2]
    // grid = 2048 (%8==0), BK=64 residency-probe kernel
    gemm_bk64_g1<<<2048, 256, 0, stream>>>(xq, w1q, b1, gmax + 0, gmax + 1, h, gmax + 2);

    quant_h_kernel<<<2048, 256, 0, stream>>>(h, hq, gmax + 2);

    // out = (hq @ w2q^T + b2) * s2 ; grid = 512 (%8==0), R7 proven path
    gemm_i8_kernel<HDIM, DDIM, false, float>
        <<<512, 256, 0, stream>>>(hq, w2q, b2, gmax + 2, gmax + 3, out, nullptr);
}